// Round 4
// baseline (42.003 us; speedup 1.0000x reference)
//
#include <hip/hip_runtime.h>
#include <math.h>

// Problem constants: B=8, P=512, G=128, C=68
#define B_ 8
#define P_ 512
#define G_ 128
#define C_ 68
#define BG (B_ * G_)   // 1024
#define BP (B_ * P_)   // 4096
#define EPS_ 1.0f      // AABB slack: excluded pairs have >1px gap -> exact 0 in ref

// Single fused kernel: one 64-thread block (1 wave) per (b,g).
//  - gt prep (CCW, degenerate, AABB) in registers
//  - 8 preds/lane AABB scan (inline pred AABB + degenerate fold),
//    ballot+mbcnt compaction -> LDS survivor list (deterministic order)
//  - survivors clipped (Sutherland-Hodgman, LDS [pt][64], conflict-free)
//  - wave shuffle (area, min-idx) argmax
//  - wave-parallel 68-wide log-softmax CE -> ce/corr in workspace
//  - last-finished block does the deterministic fixed-tree 1024-reduce
__global__ __launch_bounds__(64) void fused_kernel(
    const float* __restrict__ bboxes,   // [BP,9]
    const float* __restrict__ scores,   // [BP,C]
    const float* __restrict__ polys,    // [BG,4,2]
    const int*   __restrict__ labels,   // [BG]
    float* __restrict__ ce_ws,          // [BG]
    int*   __restrict__ corr_ws,        // [BG]
    unsigned int* __restrict__ counter, // [1], zeroed by memsetAsync
    float* __restrict__ out)            // [3]
{
#pragma clang fp contract(off)
    const int bg = blockIdx.x;
    const int b  = bg >> 7;            // / G_
    const int t  = threadIdx.x;

    __shared__ int   s_idx[P_];
    __shared__ float s_px[8 * 64], s_py[8 * 64];
    __shared__ float s_qx[8 * 64], s_qy[8 * 64];

    // ---- gt prep (bit-identical to validated rounds) ----
    const float* cp = polys + (size_t)bg * 8;
    const float x0 = cp[0], y0 = cp[1], x1 = cp[2], y1 = cp[3];
    const float x2 = cp[4], y2 = cp[5], x3 = cp[6], y3 = cp[7];
    const float sa = (x0 * y1 - x1 * y0) + (x1 * y2 - x2 * y1)
                   + (x2 * y3 - x3 * y2) + (x3 * y0 - x0 * y3);
    const bool rev = (sa < 0.0f);
    float ccx[4], ccy[4];
    ccx[0] = rev ? x3 : x0; ccy[0] = rev ? y3 : y0;
    ccx[1] = rev ? x2 : x1; ccy[1] = rev ? y2 : y1;
    ccx[2] = rev ? x1 : x2; ccy[2] = rev ? y1 : y2;
    ccx[3] = rev ? x0 : x3; ccy[3] = rev ? y0 : y3;
    const bool gt_deg =
        (x0 == x1 && y0 == y1) || (x0 == x2 && y0 == y2) ||
        (x0 == x3 && y0 == y3) || (x1 == x2 && y1 == y2) ||
        (x1 == x3 && y1 == y3) || (x2 == x3 && y2 == y3);
    const float glox = fminf(fminf(x0, x1), fminf(x2, x3)) - EPS_;
    const float gloy = fminf(fminf(y0, y1), fminf(y2, y3)) - EPS_;
    const float ghix = fmaxf(fmaxf(x0, x1), fmaxf(x2, x3)) + EPS_;
    const float ghiy = fmaxf(fmaxf(y0, y1), fmaxf(y2, y3)) + EPS_;

    // ---- AABB scan: 8 preds per lane, ballot-prefix compaction ----
    const float* bbb = bboxes + (size_t)b * P_ * 9;
    int base = 0;
    #pragma unroll
    for (int r = 0; r < 8; ++r) {
        const int p = t + (r << 6);
        const float* bb = bbb + (size_t)p * 9;
        const float a0 = bb[0], a1 = bb[1], a2 = bb[2], a3 = bb[3];
        const float a4 = bb[4], a5 = bb[5], a6 = bb[6], a7 = bb[7];
        const bool deg =
            (a0 == a2 && a1 == a3) || (a0 == a4 && a1 == a5) ||
            (a0 == a6 && a1 == a7) || (a2 == a4 && a3 == a5) ||
            (a2 == a6 && a3 == a7) || (a4 == a6 && a5 == a7);
        const float lox = fminf(fminf(a0, a2), fminf(a4, a6));
        const float loy = fminf(fminf(a1, a3), fminf(a5, a7));
        const float hix = fmaxf(fmaxf(a0, a2), fmaxf(a4, a6));
        const float hiy = fmaxf(fmaxf(a1, a3), fmaxf(a5, a7));
        const bool ov = !deg &&
            (lox <= ghix) && (glox <= hix) &&
            (loy <= ghiy) && (gloy <= hiy);
        const unsigned long long mask = __ballot(ov);
        if (ov) {
            const int pre = __builtin_amdgcn_mbcnt_hi(
                (unsigned int)(mask >> 32),
                __builtin_amdgcn_mbcnt_lo((unsigned int)mask, 0u));
            s_idx[base + pre] = p;
        }
        base += __popcll(mask);
    }
    const int ns = base;

    // ---- clip survivors (bit-identical SH) ----
    float bestA = 0.0f;
    int   bestI = 0x7fffffff;

    for (int k0 = 0; k0 < ns; k0 += 64) {
        const int k = k0 + t;
        if (k < ns) {
            const int p = s_idx[k];
            const float* bb = bbb + (size_t)p * 9;
            s_px[0 * 64 + t] = bb[0]; s_py[0 * 64 + t] = bb[1];
            s_px[1 * 64 + t] = bb[2]; s_py[1 * 64 + t] = bb[3];
            s_px[2 * 64 + t] = bb[4]; s_py[2 * 64 + t] = bb[5];
            s_px[3 * 64 + t] = bb[6]; s_py[3 * 64 + t] = bb[7];
            int n = 4;
            float* curx = s_px; float* cury = s_py;
            float* outx = s_qx; float* outy = s_qy;
            #pragma unroll
            for (int e = 0; e < 4; ++e) {
                const float eax = ccx[e], eay = ccy[e];
                const float ex = ccx[(e + 1) & 3] - eax;
                const float ey = ccy[(e + 1) & 3] - eay;
                int m = 0;
                for (int i = 0; i < n; ++i) {
                    const int j = (i + 1 == n) ? 0 : i + 1;
                    const float pxi = curx[i * 64 + t], pyi = cury[i * 64 + t];
                    const float pxj = curx[j * 64 + t], pyj = cury[j * 64 + t];
                    const float dp = ex * (pyi - eay) - ey * (pxi - eax);
                    const float dq = ex * (pyj - eay) - ey * (pxj - eax);
                    const bool inp = (dp >= 0.0f);
                    const bool inq = (dq >= 0.0f);
                    if (inp) {
                        if (m < 8) { outx[m * 64 + t] = pxi; outy[m * 64 + t] = pyi; }
                        ++m;
                    }
                    if (inp != inq) {
                        const float den = dp - dq;
                        const float tt = (den == 0.0f) ? 0.0f : dp / den;
                        if (m < 8) {
                            outx[m * 64 + t] = pxi + tt * (pxj - pxi);
                            outy[m * 64 + t] = pyi + tt * (pyj - pyi);
                        }
                        ++m;
                    }
                }
                n = (m > 8) ? 8 : m;
                float* tx = curx; curx = outx; outx = tx;
                float* ty = cury; cury = outy; outy = ty;
            }
            float s = 0.0f;
            for (int i = 0; i < n; ++i) {
                const int j = (i + 1 == n) ? 0 : i + 1;
                s += curx[i * 64 + t] * cury[j * 64 + t]
                   - curx[j * 64 + t] * cury[i * 64 + t];
            }
            const float area = fabsf(0.5f * s);
            if (area > bestA || (area == bestA && p < bestI)) {
                bestA = area; bestI = p;
            }
        }
    }

    #pragma unroll
    for (int off = 32; off; off >>= 1) {
        const float oa = __shfl_xor(bestA, off);
        const int   oi = __shfl_xor(bestI, off);
        if (oa > bestA || (oa == bestA && oi < bestI)) { bestA = oa; bestI = oi; }
    }

    const bool matched = (!gt_deg) && (bestA != 0.0f);
    const int label = labels[bg];

    if (matched) {
        const float* sc = scores + (size_t)(b * P_ + bestI) * C_;
        const float v0 = sc[t];
        const bool  h2 = (t + 64) < C_;
        const float v1 = h2 ? sc[t + 64] : -3e38f;
        float bv; int bi;
        if (v1 > v0) { bv = v1; bi = t + 64; } else { bv = v0; bi = t; }
        float mx = fmaxf(v0, v1);
        #pragma unroll
        for (int off = 32; off; off >>= 1) mx = fmaxf(mx, __shfl_xor(mx, off));
        #pragma unroll
        for (int off = 32; off; off >>= 1) {
            const float ov2 = __shfl_xor(bv, off);
            const int   oi2 = __shfl_xor(bi, off);
            if (ov2 > bv || (ov2 == bv && oi2 < bi)) { bv = ov2; bi = oi2; }
        }
        float e = expf(v0 - mx) + (h2 ? expf(v1 - mx) : 0.0f);
        #pragma unroll
        for (int off = 32; off; off >>= 1) e += __shfl_xor(e, off);
        if (t == 0) {
            ce_ws[bg]   = mx + logf(e) - sc[label];
            corr_ws[bg] = (bi == label) ? 1 : 0;
        }
    } else {
        if (t == 0) {
            ce_ws[bg]   = logf((float)C_);
            corr_ws[bg] = 0;
        }
    }

    // ---- last-block finalize (deterministic fixed tree, any finisher) ----
    __threadfence();                       // release our ce/corr write
    int last = 0;
    if (t == 0) last = (atomicAdd(counter, 1u) == (unsigned)(BG - 1)) ? 1 : 0;
    last = __shfl(last, 0);
    if (last) {
        __threadfence();                   // acquire all blocks' writes
        volatile const float* vce = ce_ws;
        volatile const int*   vcr = corr_ws;
        float a = 0.0f; int c = 0;
        #pragma unroll
        for (int r = 0; r < BG / 64; ++r) {   // fixed order: t, t+64, ...
            a += vce[t + (r << 6)];
            c += vcr[t + (r << 6)];
        }
        #pragma unroll
        for (int off = 32; off; off >>= 1) {
            a += __shfl_xor(a, off);
            c += __shfl_xor(c, off);
        }
        if (t == 0) {
            out[0] = a / (float)BG;   // mean ce
            out[1] = (float)BG;       // total_number
            out[2] = (float)c;        // rec_correct
        }
    }
}

extern "C" void kernel_launch(void* const* d_in, const int* in_sizes, int n_in,
                              void* d_out, int out_size, void* d_ws, size_t ws_size,
                              hipStream_t stream) {
    const float* bboxes = (const float*)d_in[0];   // [B,P,9]
    const float* scores = (const float*)d_in[1];   // [B,P,C]
    const float* polys  = (const float*)d_in[2];   // [B,G,4,2]
    const int*   labels = (const int*)d_in[3];     // [B,G]
    float* out = (float*)d_out;

    float*        ce  = (float*)d_ws;                               // [BG]
    int*          cr  = (int*)((char*)d_ws + BG * sizeof(float));   // [BG]
    unsigned int* cnt = (unsigned int*)((char*)d_ws + 2 * BG * sizeof(float));

    hipMemsetAsync(cnt, 0, sizeof(unsigned int), stream);
    fused_kernel<<<BG, 64, 0, stream>>>(bboxes, scores, polys, labels,
                                        ce, cr, cnt, out);
}